// Round 5
// baseline (442.950 us; speedup 1.0000x reference)
//
#include <hip/hip_runtime.h>
#include <math.h>

#define SS 4096
#define EE 1024
#define HH 16
#define DD 64
#define RMAX 128   // max supported segment length (actual ~64±8)
#define NBLK 256

// ---------------------------------------------------------------------------
// ws layout (floats):
//   int[0..1]   : meta (s0, L)          (written by init)
//   int[32],[33]: barrier counter, generation (zeroed by init)
//   [64..]      : sumx[E]
//   [64+E..]    : bgA[E]  (V_all = S*bv + Wv.sumx)
//   [64+2E..]   : mwv[E]  (atomic SUM of wv rows; /L folded into out)
//   float 4096  : qb[RMAX][E], kb, vb, kt[E][RMAX], part[256][E],
//                 ypart[12][RMAX][E]
// All buffers are written before read within each call (poison-safe).
// ---------------------------------------------------------------------------

__device__ __forceinline__ void gbar(int* cnt, int* gen) {
    __syncthreads();
    if (threadIdx.x == 0) {
        int g = __hip_atomic_load(gen, __ATOMIC_RELAXED, __HIP_MEMORY_SCOPE_AGENT);
        __threadfence();
        int t = __hip_atomic_fetch_add(cnt, 1, __ATOMIC_ACQ_REL, __HIP_MEMORY_SCOPE_AGENT);
        if (t == NBLK - 1) {
            __hip_atomic_store(cnt, 0, __ATOMIC_RELAXED, __HIP_MEMORY_SCOPE_AGENT);
            __hip_atomic_fetch_add(gen, 1, __ATOMIC_RELEASE, __HIP_MEMORY_SCOPE_AGENT);
        } else {
            while (__hip_atomic_load(gen, __ATOMIC_ACQUIRE, __HIP_MEMORY_SCOPE_AGENT) == g)
                __builtin_amdgcn_s_sleep(1);
        }
        __threadfence();
    }
    __syncthreads();
}

// zero the 16 KB header (incl. barrier state) + segment scan -> meta
__global__ __launch_bounds__(256) void init_kernel(const int* __restrict__ seg,
                                                   const int* __restrict__ posp,
                                                   float* __restrict__ ws) {
    int tid = threadIdx.x;
    float4 z = make_float4(0.f, 0.f, 0.f, 0.f);
    float4* w4 = (float4*)ws;
    for (int i = tid; i < 1024; i += 256) w4[i] = z;
    __shared__ int smin, smax;
    if (tid == 0) { smin = SS; smax = -1; }
    __syncthreads();
    int sid = seg[posp[0]];
    int lmin = SS, lmax = -1;
    for (int i = tid; i < SS; i += 256)
        if (seg[i] == sid) { lmin = min(lmin, i); lmax = max(lmax, i); }
    atomicMin(&smin, lmin);
    atomicMax(&smax, lmax);
    __syncthreads();
    if (tid == 0) {
        int L = smax - smin + 1;
        if (L > RMAX) L = RMAX;
        ((int*)ws)[0] = smin;
        ((int*)ws)[1] = L;
    }
}

__global__ __launch_bounds__(256) void mega_kernel(
    const float* __restrict__ x,
    const float* __restrict__ Wq, const float* __restrict__ bq,
    const float* __restrict__ Wk, const float* __restrict__ bk,
    const float* __restrict__ Wv, const float* __restrict__ bv,
    const float* __restrict__ Wo, const float* __restrict__ bo,
    float* __restrict__ ws, float* __restrict__ out) {
    __shared__ float lds[128 * 65 + 128 * 36];   // 51.7 KB (proj); reused by attn
    int* meta = (int*)ws;
    int* cnt  = (int*)ws + 32;
    int* gen  = (int*)ws + 33;
    float* sumx = ws + 64;
    float* bgA  = ws + 64 + EE;
    float* mwv  = ws + 64 + 2 * EE;
    float* qb   = ws + 4096;
    float* kb   = qb + RMAX * EE;
    float* vb   = kb + RMAX * EE;
    float* kt   = vb + RMAX * EE;
    float* part = kt + RMAX * EE;
    float* ypart = part + 256 * EE;

    int bid = blockIdx.x, tid = threadIdx.x;
    int lane = tid & 63, wave = tid >> 6;
    int s0 = meta[0], L = meta[1];

    // ---- P1: x column-sum partials (block b owns rows 16b..16b+15) ----
    {
        int r0 = bid * 16;
        const float4* x4 = (const float4*)x;
        float4 a = make_float4(0.f, 0.f, 0.f, 0.f);
#pragma unroll 4
        for (int r = r0; r < r0 + 16; ++r) {
            float4 v = x4[(size_t)r * 256 + tid];
            a.x += v.x; a.y += v.y; a.z += v.z; a.w += v.w;
        }
        ((float4*)part)[(size_t)bid * 256 + tid] = a;
    }
    gbar(cnt, gen);

    // ---- P2: sumx reduce (blocks 252-255) || proj partials (blocks 0-251) ----
    if (bid >= 252) {
        int e = (bid - 252) * 256 + tid;
        float s = 0.f;
#pragma unroll 8
        for (int c = 0; c < 256; ++c) s += part[(size_t)c * EE + e];
        sumx[e] = s;                      // single writer, plain store
    } else {
        int nry = (L + 63) >> 6;
        int items = 384 * nry;
        float* xs  = lds;                 // [128][65]
        float* wsm = lds + 128 * 65;      // [128][36]
        for (int it = bid; it < items; it += 252) {
            int ry = it / 384, rem = it % 384;
            int m = rem >> 7, rem2 = rem & 127;
            int kc = rem2 >> 5, et = rem2 & 31;
            int r0 = ry * 64;
            const float* W = (m == 0) ? Wq : ((m == 1) ? Wk : Wv);
            int eo = wave << 3;
            float acc[8] = {0.f, 0.f, 0.f, 0.f, 0.f, 0.f, 0.f, 0.f};
            for (int rr = 0; rr < 2; ++rr) {
                int k0 = kc * 256 + rr * 128;
                __syncthreads();
                for (int idx = tid; idx < 2048; idx += 256) {
                    int k4 = idx & 31, r = idx >> 5;
                    float4 v = make_float4(0.f, 0.f, 0.f, 0.f);
                    if (r0 + r < L)
                        v = *(const float4*)(x + (size_t)(s0 + r0 + r) * EE + k0 + k4 * 4);
                    xs[(k4 * 4 + 0) * 65 + r] = v.x;
                    xs[(k4 * 4 + 1) * 65 + r] = v.y;
                    xs[(k4 * 4 + 2) * 65 + r] = v.z;
                    xs[(k4 * 4 + 3) * 65 + r] = v.w;
                }
                for (int idx = tid; idx < 1024; idx += 256) {
                    int k4 = idx & 31, e = idx >> 5;
                    float4 v = *(const float4*)(W + (size_t)(et * 32 + e) * EE + k0 + k4 * 4);
                    wsm[(k4 * 4 + 0) * 36 + e] = v.x;
                    wsm[(k4 * 4 + 1) * 36 + e] = v.y;
                    wsm[(k4 * 4 + 2) * 36 + e] = v.z;
                    wsm[(k4 * 4 + 3) * 36 + e] = v.w;
                }
                __syncthreads();
#pragma unroll 4
                for (int k = 0; k < 128; ++k) {
                    float xr = xs[k * 65 + lane];
                    const float4* wp = (const float4*)&wsm[k * 36 + eo];
                    float4 w0 = wp[0], w1 = wp[1];
                    acc[0] += w0.x * xr; acc[1] += w0.y * xr;
                    acc[2] += w0.z * xr; acc[3] += w0.w * xr;
                    acc[4] += w1.x * xr; acc[5] += w1.y * xr;
                    acc[6] += w1.z * xr; acc[7] += w1.w * xr;
                }
            }
            float* dst = ypart + ((size_t)(m * 4 + kc) * RMAX + (r0 + lane)) * EE + et * 32 + eo;
            *(float4*)dst       = make_float4(acc[0], acc[1], acc[2], acc[3]);
            *(float4*)(dst + 4) = make_float4(acc[4], acc[5], acc[6], acc[7]);
        }
    }
    gbar(cnt, gen);

    // ---- P3: projred + K-transpose (blocks 0-191) || V_all GEMV (192-255) ----
    if (bid < 192) {
        for (int it = bid; it < 3 * L; it += 192) {
            int m = it / L, r = it - m * L;
            const size_t slab = (size_t)RMAX * 256;     // float4 units
            const float4* yp = (const float4*)ypart + ((size_t)(m * 4) * RMAX + r) * 256;
            int c = tid;
            float4 a0 = yp[c], a1 = yp[slab + c], a2 = yp[2 * slab + c], a3 = yp[3 * slab + c];
            const float* b = (m == 0) ? bq : ((m == 1) ? bk : bv);
            float4 bb = ((const float4*)b)[c];
            float4 o = make_float4(a0.x + a1.x + a2.x + a3.x + bb.x,
                                   a0.y + a1.y + a2.y + a3.y + bb.y,
                                   a0.z + a1.z + a2.z + a3.z + bb.z,
                                   a0.w + a1.w + a2.w + a3.w + bb.w);
            float* y = (m == 0) ? qb : ((m == 1) ? kb : vb);
            ((float4*)(y + (size_t)r * EE))[c] = o;
            if (m == 1) {
                kt[(size_t)(4 * c + 0) * RMAX + r] = o.x;
                kt[(size_t)(4 * c + 1) * RMAX + r] = o.y;
                kt[(size_t)(4 * c + 2) * RMAX + r] = o.z;
                kt[(size_t)(4 * c + 3) * RMAX + r] = o.w;
            }
        }
    } else {
        int w = (bid - 192) * 4 + wave;   // 0..255, each wave does 4 e's
        const float4* s4 = (const float4*)sumx;
        for (int jj = 0; jj < 4; ++jj) {
            int e = w * 4 + jj;
            const float4* w4 = (const float4*)(Wv + (size_t)e * EE);
            float p = 0.f;
#pragma unroll
            for (int j = 0; j < 4; ++j) {
                float4 wv4 = w4[j * 64 + lane], sx = s4[j * 64 + lane];
                p += wv4.x * sx.x + wv4.y * sx.y + wv4.z * sx.z + wv4.w * sx.w;
            }
#pragma unroll
            for (int off = 32; off; off >>= 1) p += __shfl_xor(p, off);
            if (lane == 0) bgA[e] = p + (float)SS * bv[e];
        }
    }
    gbar(cnt, gen);

    // ---- P4: attention (one wave per (row, head); vsum fused for background) ----
    {
        int gw = bid * 4 + wave;
        int nt = (L + 63) >> 6;
        float* sc = lds + wave * 128;
        for (int it = gw; it < L * HH; it += NBLK * 4) {
            int h = it & (HH - 1), sl = it >> 4;
            int hD = h * DD;
            float qreg = qb[(size_t)sl * EE + hD + lane];
            const float* kth = kt + (size_t)hD * RMAX;
            float mmax = 0.f;   // L < SS: zero background participates in the row max
            for (int t0 = 0; t0 < nt; ++t0) {
                float s = 0.f;
                const float* kp = kth + t0 * 64 + lane;
#pragma unroll
                for (int d = 0; d < 64; ++d) s += __shfl(qreg, d) * kp[(size_t)d * RMAX];
                sc[t0 * 64 + lane] = s;
                mmax = fmaxf(mmax, (t0 * 64 + lane < L) ? s : -3.0e38f);
            }
#pragma unroll
            for (int off = 32; off; off >>= 1) mmax = fmaxf(mmax, __shfl_xor(mmax, off));
            float Zl = 0.f;
            for (int t0 = 0; t0 < nt; ++t0) {
                float wgt = (t0 * 64 + lane < L) ? __expf(sc[t0 * 64 + lane] - mmax) : 0.f;
                Zl += wgt;
                sc[t0 * 64 + lane] = wgt;
            }
#pragma unroll
            for (int off = 32; off; off >>= 1) Zl += __shfl_xor(Zl, off);
            float Z = Zl + (float)(SS - L) * __expf(-mmax);
            float acc = 0.f, vsum = 0.f;
            for (int t0 = 0; t0 < nt; ++t0) {
                const float* vp = vb + (size_t)(t0 * 64) * EE + hD + lane;
                int lim = min(64, L - t0 * 64);
                for (int tt = 0; tt < lim; ++tt) {
                    float vv = vp[(size_t)tt * EE];
                    acc  += sc[t0 * 64 + tt] * vv;
                    vsum += vv;
                }
            }
            float o = (acc + __expf(-mmax) * (bgA[hD + lane] - vsum)) / Z;
            atomicAdd(&mwv[hD + lane], o);
        }
    }
    gbar(cnt, gen);

    // ---- P5: out[e] = (mwv . Wo[e,:]) / L + bo[e] (one wave per e) ----
    {
        int e = bid * 4 + wave;
        const float4* w4 = (const float4*)(Wo + (size_t)e * EE);
        const float4* m4 = (const float4*)mwv;
        float a = 0.f;
#pragma unroll
        for (int j = 0; j < 4; ++j) {
            float4 wv4 = w4[j * 64 + lane], mm = m4[j * 64 + lane];
            a += wv4.x * mm.x + wv4.y * mm.y + wv4.z * mm.z + wv4.w * mm.w;
        }
#pragma unroll
        for (int off = 32; off; off >>= 1) a += __shfl_xor(a, off);
        if (lane == 0) out[e] = a / (float)L + bo[e];
    }
}

extern "C" void kernel_launch(void* const* d_in, const int* in_sizes, int n_in,
                              void* d_out, int out_size, void* d_ws, size_t ws_size,
                              hipStream_t stream) {
    const float* x   = (const float*)d_in[0];
    const float* Wq  = (const float*)d_in[1];
    const float* bq  = (const float*)d_in[2];
    const float* Wk  = (const float*)d_in[3];
    const float* bk  = (const float*)d_in[4];
    const float* Wv  = (const float*)d_in[5];
    const float* bv  = (const float*)d_in[6];
    const float* Wo  = (const float*)d_in[7];
    const float* bo  = (const float*)d_in[8];
    const int*   seg = (const int*)d_in[9];
    const int*   pos = (const int*)d_in[10];
    float*       out = (float*)d_out;
    float*       ws  = (float*)d_ws;

    init_kernel<<<1, 256, 0, stream>>>(seg, pos, ws);
    mega_kernel<<<NBLK, 256, 0, stream>>>(x, Wq, bq, Wk, bk, Wv, bv, Wo, bo, ws, out);
}

// Round 7
// 259.421 us; speedup vs baseline: 1.7075x; 1.7075x over previous
//
#include <hip/hip_runtime.h>
#include <math.h>

#define SS 4096
#define EE 1024
#define HH 16
#define DD 64
#define RMAX 128   // max supported segment length (actual ~64±8)
#define NBLK 512   // 2 blocks/CU; LDS 51.7KB -> 3/CU capacity, co-residency safe

// ---------------------------------------------------------------------------
// ws layout (floats):
//   int[0..1]   : meta (s0, L)          (written by init)
//   int[32],[33]: barrier counter, generation (zeroed by init)
//   [64..]      : sumx[E]
//   [64+E..]    : bgA[E]  (V_all = S*bv + Wv.sumx)
//   [64+2E..]   : mwv[E]  (atomic SUM of wv rows; /L folded into out)
//   float 4096  : qb[RMAX][E], kb, vb, kt[E][RMAX], part[NBLK][E],
//                 ypart[12][RMAX][E]
// ---------------------------------------------------------------------------

// Grid barrier. CRITICAL: spin with RELAXED loads (agent-scope relaxed atomics
// are coherent on gfx950 but do NOT emit buffer_inv); exactly one RELEASE
// fence (L2 writeback) before arrival and one ACQUIRE fence (L2 invalidate)
// after exit. Spinning on an ACQUIRE load invalidates the whole L2 per poll.
__device__ __forceinline__ void gbar(int* cnt, int* gen) {
    __syncthreads();
    if (threadIdx.x == 0) {
        __builtin_amdgcn_fence(__ATOMIC_RELEASE, "agent");
        int g = __hip_atomic_load(gen, __ATOMIC_RELAXED, __HIP_MEMORY_SCOPE_AGENT);
        int t = __hip_atomic_fetch_add(cnt, 1, __ATOMIC_RELAXED, __HIP_MEMORY_SCOPE_AGENT);
        if (t == NBLK - 1) {
            __hip_atomic_store(cnt, 0, __ATOMIC_RELAXED, __HIP_MEMORY_SCOPE_AGENT);
            __hip_atomic_store(gen, g + 1, __ATOMIC_RELAXED, __HIP_MEMORY_SCOPE_AGENT);
        } else {
            while (__hip_atomic_load(gen, __ATOMIC_RELAXED, __HIP_MEMORY_SCOPE_AGENT) == g)
                __builtin_amdgcn_s_sleep(8);
        }
        __builtin_amdgcn_fence(__ATOMIC_ACQUIRE, "agent");
    }
    __syncthreads();
}

// zero the 16 KB header (incl. barrier state) + segment scan -> meta
__global__ __launch_bounds__(256) void init_kernel(const int* __restrict__ seg,
                                                   const int* __restrict__ posp,
                                                   float* __restrict__ ws) {
    int tid = threadIdx.x;
    float4 z = make_float4(0.f, 0.f, 0.f, 0.f);
    float4* w4 = (float4*)ws;
    for (int i = tid; i < 1024; i += 256) w4[i] = z;
    __shared__ int smin, smax;
    if (tid == 0) { smin = SS; smax = -1; }
    __syncthreads();
    int sid = seg[posp[0]];
    int lmin = SS, lmax = -1;
    for (int i = tid; i < SS; i += 256)
        if (seg[i] == sid) { lmin = min(lmin, i); lmax = max(lmax, i); }
    atomicMin(&smin, lmin);
    atomicMax(&smax, lmax);
    __syncthreads();
    if (tid == 0) {
        int L = smax - smin + 1;
        if (L > RMAX) L = RMAX;
        ((int*)ws)[0] = smin;
        ((int*)ws)[1] = L;
    }
}

__global__ __launch_bounds__(256) void mega_kernel(
    const float* __restrict__ x,
    const float* __restrict__ Wq, const float* __restrict__ bq,
    const float* __restrict__ Wk, const float* __restrict__ bk,
    const float* __restrict__ Wv, const float* __restrict__ bv,
    const float* __restrict__ Wo, const float* __restrict__ bo,
    float* __restrict__ ws, float* __restrict__ out) {
    __shared__ float lds[128 * 65 + 128 * 36];   // 51.7 KB
    int* meta = (int*)ws;
    int* cnt  = (int*)ws + 32;
    int* gen  = (int*)ws + 33;
    float* sumx = ws + 64;
    float* bgA  = ws + 64 + EE;
    float* mwv  = ws + 64 + 2 * EE;
    float* qb   = ws + 4096;
    float* kb   = qb + RMAX * EE;
    float* vb   = kb + RMAX * EE;
    float* kt   = vb + RMAX * EE;
    float* part = kt + RMAX * EE;
    float* ypart = part + (size_t)NBLK * EE;

    int bid = blockIdx.x, tid = threadIdx.x;
    int lane = tid & 63, wave = tid >> 6;
    int s0 = meta[0], L = meta[1];
    int Lp = (L + 63) & ~63;          // zero-padded row count (64 or 128)
    int nry = Lp >> 6;

    // ---- P1: x column-sum partials (block b owns rows 8b..8b+7) ----
    {
        int r0 = bid * (SS / NBLK);
        const float4* x4 = (const float4*)x;
        float4 a = make_float4(0.f, 0.f, 0.f, 0.f);
#pragma unroll
        for (int r = 0; r < SS / NBLK; ++r) {
            float4 v = x4[(size_t)(r0 + r) * 256 + tid];
            a.x += v.x; a.y += v.y; a.z += v.z; a.w += v.w;
        }
        ((float4*)part)[(size_t)bid * 256 + tid] = a;
    }
    gbar(cnt, gen);

    // ---- P2: proj partials (blocks 0-383) || sumx reduce (blocks 384-447) ----
    if (bid < 384) {
        int items = 384 * nry;
        float* xs  = lds;                 // [128][65]
        float* wsm = lds + 128 * 65;      // [128][36]
        for (int it = bid; it < items; it += 384) {
            int ry = it / 384, rem = it % 384;
            int m = rem >> 7, rem2 = rem & 127;
            int kc = rem2 >> 5, et = rem2 & 31;
            int r0 = ry * 64;
            const float* W = (m == 0) ? Wq : ((m == 1) ? Wk : Wv);
            int eo = wave << 3;
            float acc[8] = {0.f, 0.f, 0.f, 0.f, 0.f, 0.f, 0.f, 0.f};
            for (int rr = 0; rr < 2; ++rr) {
                int k0 = kc * 256 + rr * 128;
                __syncthreads();
                for (int idx = tid; idx < 2048; idx += 256) {
                    int k4 = idx & 31, r = idx >> 5;
                    float4 v = make_float4(0.f, 0.f, 0.f, 0.f);
                    if (r0 + r < L)
                        v = *(const float4*)(x + (size_t)(s0 + r0 + r) * EE + k0 + k4 * 4);
                    xs[(k4 * 4 + 0) * 65 + r] = v.x;
                    xs[(k4 * 4 + 1) * 65 + r] = v.y;
                    xs[(k4 * 4 + 2) * 65 + r] = v.z;
                    xs[(k4 * 4 + 3) * 65 + r] = v.w;
                }
                for (int idx = tid; idx < 1024; idx += 256) {
                    int k4 = idx & 31, e = idx >> 5;
                    float4 v = *(const float4*)(W + (size_t)(et * 32 + e) * EE + k0 + k4 * 4);
                    wsm[(k4 * 4 + 0) * 36 + e] = v.x;
                    wsm[(k4 * 4 + 1) * 36 + e] = v.y;
                    wsm[(k4 * 4 + 2) * 36 + e] = v.z;
                    wsm[(k4 * 4 + 3) * 36 + e] = v.w;
                }
                __syncthreads();
#pragma unroll 4
                for (int k = 0; k < 128; ++k) {
                    float xr = xs[k * 65 + lane];
                    const float4* wp = (const float4*)&wsm[k * 36 + eo];
                    float4 w0 = wp[0], w1 = wp[1];
                    acc[0] += w0.x * xr; acc[1] += w0.y * xr;
                    acc[2] += w0.z * xr; acc[3] += w0.w * xr;
                    acc[4] += w1.x * xr; acc[5] += w1.y * xr;
                    acc[6] += w1.z * xr; acc[7] += w1.w * xr;
                }
            }
            float* dst = ypart + ((size_t)(m * 4 + kc) * RMAX + (r0 + lane)) * EE + et * 32 + eo;
            *(float4*)dst       = make_float4(acc[0], acc[1], acc[2], acc[3]);
            *(float4*)(dst + 4) = make_float4(acc[4], acc[5], acc[6], acc[7]);
        }
    } else if (bid < 448) {
        // 64 blocks; block b owns 16 e's; 16 threads per e; 32 unrolled loads each
        int b = bid - 384;
        int e  = b * 16 + (tid >> 4);
        int c0 = tid & 15;
        float s = 0.f;
#pragma unroll
        for (int j = 0; j < NBLK / 16; ++j) s += part[(size_t)(c0 + j * 16) * EE + e];
#pragma unroll
        for (int off = 8; off; off >>= 1) s += __shfl_xor(s, off, 16);
        if (c0 == 0) sumx[e] = s;
    }
    gbar(cnt, gen);

    // ---- P3: projred + K-transpose (rows >= L zeroed) || V_all GEMV ----
    if (bid < 384) {
        for (int it = bid; it < 3 * Lp; it += 384) {
            int m = it / Lp, r = it - m * Lp;
            float4 o = make_float4(0.f, 0.f, 0.f, 0.f);
            int c = tid;
            if (r < L) {
                const size_t slab = (size_t)RMAX * 256;     // float4 units
                const float4* yp = (const float4*)ypart + ((size_t)(m * 4) * RMAX + r) * 256;
                float4 a0 = yp[c], a1 = yp[slab + c], a2 = yp[2 * slab + c], a3 = yp[3 * slab + c];
                const float* b = (m == 0) ? bq : ((m == 1) ? bk : bv);
                float4 bb = ((const float4*)b)[c];
                o = make_float4(a0.x + a1.x + a2.x + a3.x + bb.x,
                                a0.y + a1.y + a2.y + a3.y + bb.y,
                                a0.z + a1.z + a2.z + a3.z + bb.z,
                                a0.w + a1.w + a2.w + a3.w + bb.w);
            }
            float* y = (m == 0) ? qb : ((m == 1) ? kb : vb);
            ((float4*)(y + (size_t)r * EE))[c] = o;
            if (m == 1) {
                kt[(size_t)(4 * c + 0) * RMAX + r] = o.x;
                kt[(size_t)(4 * c + 1) * RMAX + r] = o.y;
                kt[(size_t)(4 * c + 2) * RMAX + r] = o.z;
                kt[(size_t)(4 * c + 3) * RMAX + r] = o.w;
            }
        }
    } else {
        int w = (bid - 384) * 4 + wave;   // 0..511
        const float4* s4 = (const float4*)sumx;
        for (int e = w; e < EE; e += 512) {
            const float4* w4 = (const float4*)(Wv + (size_t)e * EE);
            float p = 0.f;
#pragma unroll
            for (int j = 0; j < 4; ++j) {
                float4 wv4 = w4[j * 64 + lane], sx = s4[j * 64 + lane];
                p += wv4.x * sx.x + wv4.y * sx.y + wv4.z * sx.z + wv4.w * sx.w;
            }
#pragma unroll
            for (int off = 32; off; off >>= 1) p += __shfl_xor(p, off);
            if (lane == 0) bgA[e] = p + (float)SS * bv[e];
        }
    }
    gbar(cnt, gen);

    // ---- P4: attention (one wave per (row, head); vsum fused background) ----
    {
        int gw = bid * 4 + wave;
        int nt = Lp >> 6;
        float* sc = lds + wave * 128;
        for (int it = gw; it < L * HH; it += NBLK * 4) {
            int h = it & (HH - 1), sl = it >> 4;
            int hD = h * DD;
            float qreg = qb[(size_t)sl * EE + hD + lane];
            const float* kth = kt + (size_t)hD * RMAX;
            float mmax = 0.f;   // L < SS: zero background participates in row max
            for (int t0 = 0; t0 < nt; ++t0) {
                float s = 0.f;
                const float* kp = kth + t0 * 64 + lane;
#pragma unroll
                for (int d = 0; d < 64; ++d) s += __shfl(qreg, d) * kp[(size_t)d * RMAX];
                sc[t0 * 64 + lane] = s;
                mmax = fmaxf(mmax, (t0 * 64 + lane < L) ? s : -3.0e38f);
            }
#pragma unroll
            for (int off = 32; off; off >>= 1) mmax = fmaxf(mmax, __shfl_xor(mmax, off));
            float Zl = 0.f;
            for (int t0 = 0; t0 < nt; ++t0) {
                float wgt = (t0 * 64 + lane < L) ? __expf(sc[t0 * 64 + lane] - mmax) : 0.f;
                Zl += wgt;
                sc[t0 * 64 + lane] = wgt;   // padded slots hold 0
            }
#pragma unroll
            for (int off = 32; off; off >>= 1) Zl += __shfl_xor(Zl, off);
            float Z = Zl + (float)(SS - L) * __expf(-mmax);
            float acc = 0.f, vsum = 0.f;
            for (int t0 = 0; t0 < nt; ++t0) {
                const float* vp = vb + (size_t)(t0 * 64) * EE + hD + lane;
#pragma unroll
                for (int tt = 0; tt < 64; ++tt) {   // fixed trip: 64 loads in flight
                    float vv = vp[(size_t)tt * EE]; // padded rows are zero
                    acc  += sc[t0 * 64 + tt] * vv;
                    vsum += vv;
                }
            }
            float o = (acc + __expf(-mmax) * (bgA[hD + lane] - vsum)) / Z;
            atomicAdd(&mwv[hD + lane], o);
        }
    }
    gbar(cnt, gen);

    // ---- P5: out[e] = (mwv . Wo[e,:]) / L + bo[e] (one wave per e) ----
    for (int e = bid * 4 + wave; e < EE; e += NBLK * 4) {
        const float4* w4 = (const float4*)(Wo + (size_t)e * EE);
        const float4* m4 = (const float4*)mwv;
        float a = 0.f;
#pragma unroll
        for (int j = 0; j < 4; ++j) {
            float4 wv4 = w4[j * 64 + lane], mm = m4[j * 64 + lane];
            a += wv4.x * mm.x + wv4.y * mm.y + wv4.z * mm.z + wv4.w * mm.w;
        }
#pragma unroll
        for (int off = 32; off; off >>= 1) a += __shfl_xor(a, off);
        if (lane == 0) out[e] = a / (float)L + bo[e];
    }
}

extern "C" void kernel_launch(void* const* d_in, const int* in_sizes, int n_in,
                              void* d_out, int out_size, void* d_ws, size_t ws_size,
                              hipStream_t stream) {
    const float* x   = (const float*)d_in[0];
    const float* Wq  = (const float*)d_in[1];
    const float* bq  = (const float*)d_in[2];
    const float* Wk  = (const float*)d_in[3];
    const float* bk  = (const float*)d_in[4];
    const float* Wv  = (const float*)d_in[5];
    const float* bv  = (const float*)d_in[6];
    const float* Wo  = (const float*)d_in[7];
    const float* bo  = (const float*)d_in[8];
    const int*   seg = (const int*)d_in[9];
    const int*   pos = (const int*)d_in[10];
    float*       out = (float*)d_out;
    float*       ws  = (float*)d_ws;

    init_kernel<<<1, 256, 0, stream>>>(seg, pos, ws);
    mega_kernel<<<NBLK, 256, 0, stream>>>(x, Wq, bq, Wk, bk, Wv, bv, Wo, bo, ws, out);
}

// Round 8
// 197.928 us; speedup vs baseline: 2.2379x; 1.3107x over previous
//
#include <hip/hip_runtime.h>
#include <math.h>

#define SS 4096
#define EE 1024
#define HH 16
#define DD 64
#define RMAX 128     // max supported segment length (actual ~64, 8 sigma safe)
#define NCOL 128     // colsum blocks (32 rows each)
#define NPROJ 384    // proj blocks: 3 m x 64 etiles x 2 row-blocks
#define RSPLIT 2     // row-split blocks per head in attn

// ---------------------------------------------------------------------------
// ws layout (floats):
//   [0]              : part[NCOL][EE]   x column-sum partials (512 KB)
//   [NCOL*EE]        : qb[RMAX][EE]     zero-padded to Lp rows
//   [+RMAX*EE]       : kb[RMAX][EE]
//   [+RMAX*EE]       : vb[RMAX][EE]
// No global barrier, no global meta: every block does its own segment scan
// (seg is 16 KB, L2-broadcast, ~1 us). Two dispatches; the dispatch boundary
// is the only grid-wide sync.
// ---------------------------------------------------------------------------

__device__ __forceinline__ void seg_scan(const int* __restrict__ seg,
                                         const int* __restrict__ posp,
                                         int* sh, int& s0, int& L) {
    if (threadIdx.x == 0) { sh[0] = SS; sh[1] = -1; }
    __syncthreads();
    int sid = seg[posp[0]];
    int lmin = SS, lmax = -1;
    for (int i = threadIdx.x; i < SS; i += 256)
        if (seg[i] == sid) { lmin = min(lmin, i); lmax = max(lmax, i); }
#pragma unroll
    for (int off = 32; off; off >>= 1) {
        lmin = min(lmin, __shfl_xor(lmin, off));
        lmax = max(lmax, __shfl_xor(lmax, off));
    }
    if ((threadIdx.x & 63) == 0) { atomicMin(&sh[0], lmin); atomicMax(&sh[1], lmax); }
    __syncthreads();
    s0 = sh[0];
    L  = sh[1] - sh[0] + 1;
    if (L > RMAX) L = RMAX;
    if (L < 1)    L = 1;
}

// ---------------- Dispatch 1: colsum partials || QKV projection ----------------
__global__ __launch_bounds__(256) void main_kernel(
    const float* __restrict__ x,
    const float* __restrict__ Wq, const float* __restrict__ bq,
    const float* __restrict__ Wk, const float* __restrict__ bk,
    const float* __restrict__ Wv, const float* __restrict__ bv,
    const float* __restrict__ bo,
    const int* __restrict__ seg, const int* __restrict__ posp,
    float* __restrict__ ws, float* __restrict__ out) {
    __shared__ float xs[128 * 65];   // [k][r]
    __shared__ float ws2[128 * 20];  // [k][e], 16 e per block
    __shared__ int   sh[2];
    float* part = ws;
    float* qb   = ws + (size_t)NCOL * EE;
    float* kb   = qb + (size_t)RMAX * EE;
    float* vb   = kb + (size_t)RMAX * EE;

    int bid = blockIdx.x, tid = threadIdx.x;
    int lane = tid & 63, wave = tid >> 6;

    if (bid < NCOL) {
        // ---- colsum: 32 rows per block, float4 streaming ----
        int r0 = bid * (SS / NCOL);
        const float4* x4 = (const float4*)x;
        float4 a = make_float4(0.f, 0.f, 0.f, 0.f);
#pragma unroll 8
        for (int r = 0; r < SS / NCOL; ++r) {
            float4 v = x4[(size_t)(r0 + r) * 256 + tid];
            a.x += v.x; a.y += v.y; a.z += v.z; a.w += v.w;
        }
        ((float4*)part)[(size_t)bid * 256 + tid] = a;
        if (bid == 0)  // initialize out = bo (attn dispatch atomically adds)
            ((float4*)out)[tid] = ((const float4*)bo)[tid];
        return;
    }

    // ---- projection: full K per block, 16 output cols, 64 rows ----
    int pid  = bid - NCOL;           // 0..383
    int m    = pid % 3;
    int rest = pid / 3;              // 0..127
    int et   = rest & 63;            // 16-col tile
    int ry   = rest >> 6;            // row-block 0/1

    int s0, L;
    seg_scan(seg, posp, sh, s0, L);
    int Lp = (L + 63) & ~63;
    int r0 = ry * 64;
    if (r0 >= Lp) return;

    const float* W = (m == 0) ? Wq : ((m == 1) ? Wk : Wv);
    const float* b = (m == 0) ? bq : ((m == 1) ? bk : bv);
    float*       y = (m == 0) ? qb : ((m == 1) ? kb : vb);

    float acc0 = 0.f, acc1 = 0.f, acc2 = 0.f, acc3 = 0.f;
    for (int kr = 0; kr < 8; ++kr) {
        int k0 = kr * 128;
        __syncthreads();
        for (int idx = tid; idx < 2048; idx += 256) {   // xs: 64 r x 32 k4
            int k4 = idx & 31, r = idx >> 5;
            float4 v = make_float4(0.f, 0.f, 0.f, 0.f);
            if (r0 + r < L)
                v = *(const float4*)(x + (size_t)(s0 + r0 + r) * EE + k0 + k4 * 4);
            xs[(k4 * 4 + 0) * 65 + r] = v.x;
            xs[(k4 * 4 + 1) * 65 + r] = v.y;
            xs[(k4 * 4 + 2) * 65 + r] = v.z;
            xs[(k4 * 4 + 3) * 65 + r] = v.w;
        }
        for (int idx = tid; idx < 512; idx += 256) {    // ws2: 16 e x 32 k4
            int k4 = idx & 31, e = idx >> 5;
            float4 v = *(const float4*)(W + (size_t)(et * 16 + e) * EE + k0 + k4 * 4);
            ws2[(k4 * 4 + 0) * 20 + e] = v.x;
            ws2[(k4 * 4 + 1) * 20 + e] = v.y;
            ws2[(k4 * 4 + 2) * 20 + e] = v.z;
            ws2[(k4 * 4 + 3) * 20 + e] = v.w;
        }
        __syncthreads();
#pragma unroll 8
        for (int k = 0; k < 128; ++k) {
            float xr = xs[k * 65 + lane];
            float4 wv = *(const float4*)&ws2[k * 20 + (wave << 2)];
            acc0 += wv.x * xr; acc1 += wv.y * xr;
            acc2 += wv.z * xr; acc3 += wv.w * xr;
        }
    }
    int rg = r0 + lane;               // < Lp always
    float4 res = make_float4(0.f, 0.f, 0.f, 0.f);
    if (rg < L) {
        float4 bb = *(const float4*)&b[et * 16 + (wave << 2)];
        res = make_float4(acc0 + bb.x, acc1 + bb.y, acc2 + bb.z, acc3 + bb.w);
    }
    *(float4*)(y + (size_t)rg * EE + et * 16 + (wave << 2)) = res;
}

// ---------------- Dispatch 2: per-head attention + Wo partial ----------------
__global__ __launch_bounds__(256) void attn_kernel(
    const float* __restrict__ Wv, const float* __restrict__ bv,
    const float* __restrict__ Wo,
    const int* __restrict__ seg, const int* __restrict__ posp,
    float* __restrict__ ws, float* __restrict__ out) {
    __shared__ float kT[64 * 129];      // [d][t], stride 129 (odd)
    __shared__ float sc[4 * 128];       // per-wave weight rows
    __shared__ float sxl[EE];           // reduced sumx
    __shared__ float bgh[64];           // V_all slice; reused as mwh
    __shared__ float vsum[64];
    __shared__ float mwp[4][64];
    __shared__ int   sh[2];
    const float* part = ws;
    const float* qb   = ws + (size_t)NCOL * EE;
    const float* kb   = qb + (size_t)RMAX * EE;
    const float* vb   = kb + (size_t)RMAX * EE;

    int bid = blockIdx.x, tid = threadIdx.x;
    int lane = tid & 63, wave = tid >> 6;
    int h    = bid / RSPLIT;
    int half = bid % RSPLIT;
    int hD   = h * DD;

    int s0, L;
    seg_scan(seg, posp, sh, s0, L);
    int Lp = (L + 63) & ~63;
    int nt = Lp >> 6;

    // sumx reduce: thread owns one float4 column, 128 partial rows
    {
        const float4* p4 = (const float4*)part;
        float4 s = make_float4(0.f, 0.f, 0.f, 0.f);
#pragma unroll 8
        for (int c = 0; c < NCOL; ++c) {
            float4 v = p4[(size_t)c * 256 + tid];
            s.x += v.x; s.y += v.y; s.z += v.z; s.w += v.w;
        }
        ((float4*)sxl)[tid] = s;
    }
    __syncthreads();

    // bgh[d] = S*bv[hD+d] + Wv[hD+d,:].sumx   (thread quad per d)
    {
        int d = tid >> 2, q = tid & 3;
        const float4* wr = (const float4*)(Wv + (size_t)(hD + d) * EE + q * 256);
        const float4* sx = (const float4*)(sxl + q * 256);
        float p = 0.f;
#pragma unroll
        for (int j = 0; j < 64; ++j) {
            float4 w = wr[j], s = sx[j];
            p += w.x * s.x + w.y * s.y + w.z * s.z + w.w * s.w;
        }
        p += __shfl_xor(p, 1);
        p += __shfl_xor(p, 2);
        if (q == 0) bgh[d] = p + (float)SS * bv[hD + d];
    }
    // vsum[d] = sum_t vb[t][hD+d] (padded rows are zero)
    {
        int d = tid >> 2, q = tid & 3;
        float s = 0.f;
        for (int t = q; t < Lp; t += 4) s += vb[(size_t)t * EE + hD + d];
        s += __shfl_xor(s, 1);
        s += __shfl_xor(s, 2);
        if (q == 0) vsum[d] = s;
    }
    // stage K transposed: kT[d][t] = kb[t][hD+d]
    for (int idx = tid; idx < 64 * Lp; idx += 256) {
        int d = idx & 63, t = idx >> 6;
        kT[d * 129 + t] = kb[(size_t)t * EE + hD + d];
    }
    __syncthreads();

    // rows phase: this block handles rows [half*Lp/2, (half+1)*Lp/2) clamped to L
    float mw = 0.f;
    {
        int rlo = half * (Lp / RSPLIT);
        int rhi = (half + 1) * (Lp / RSPLIT);
        if (rhi > L) rhi = L;
        float* scw = sc + wave * 128;
        for (int r = rlo + wave; r < rhi; r += 4) {
            float qreg = qb[(size_t)r * EE + hD + lane];
            float mmax = 0.f;    // zero background participates in row max
            for (int c = 0; c < nt; ++c) {
                float s = 0.f;
                const float* kp = kT + c * 64 + lane;
#pragma unroll
                for (int d = 0; d < 64; ++d) s += __shfl(qreg, d) * kp[d * 129];
                scw[c * 64 + lane] = s;
                mmax = fmaxf(mmax, (c * 64 + lane) < L ? s : -3.0e38f);
            }
#pragma unroll
            for (int off = 32; off; off >>= 1) mmax = fmaxf(mmax, __shfl_xor(mmax, off));
            float Zl = 0.f;
            for (int c = 0; c < nt; ++c) {
                float w = ((c * 64 + lane) < L) ? __expf(scw[c * 64 + lane] - mmax) : 0.f;
                Zl += w;
                scw[c * 64 + lane] = w;
            }
#pragma unroll
            for (int off = 32; off; off >>= 1) Zl += __shfl_xor(Zl, off);
            float Z = Zl + (float)(SS - L) * __expf(-mmax);
            float acc = 0.f;
            for (int c = 0; c < nt; ++c) {
                const float* vp  = vb + (size_t)(c * 64) * EE + hD + lane;
                const float* scc = scw + c * 64;
#pragma unroll 16
                for (int tt = 0; tt < 64; ++tt) acc += scc[tt] * vp[(size_t)tt * EE];
            }
            float o = (acc + __expf(-mmax) * (bgh[lane] - vsum[lane])) / Z;
            mw += o;
        }
    }
    mwp[wave][lane] = mw;
    __syncthreads();
    if (tid < 64) bgh[tid] = mwp[0][tid] + mwp[1][tid] + mwp[2][tid] + mwp[3][tid];
    __syncthreads();

    // Wo partial: out[e] += Wo[e, hD:hD+64] . mwh / L
    {
        float invL = 1.0f / (float)L;
        const float4* m4 = (const float4*)bgh;
        for (int e = tid; e < EE; e += 256) {
            const float4* wr = (const float4*)(Wo + (size_t)e * EE + hD);
            float p = 0.f;
#pragma unroll
            for (int j = 0; j < 16; ++j) {
                float4 w = wr[j], mm = m4[j];
                p += w.x * mm.x + w.y * mm.y + w.z * mm.z + w.w * mm.w;
            }
            atomicAdd(&out[e], p * invL);
        }
    }
}

extern "C" void kernel_launch(void* const* d_in, const int* in_sizes, int n_in,
                              void* d_out, int out_size, void* d_ws, size_t ws_size,
                              hipStream_t stream) {
    const float* x   = (const float*)d_in[0];
    const float* Wq  = (const float*)d_in[1];
    const float* bq  = (const float*)d_in[2];
    const float* Wk  = (const float*)d_in[3];
    const float* bk  = (const float*)d_in[4];
    const float* Wv  = (const float*)d_in[5];
    const float* bv  = (const float*)d_in[6];
    const float* Wo  = (const float*)d_in[7];
    const float* bo  = (const float*)d_in[8];
    const int*   seg = (const int*)d_in[9];
    const int*   pos = (const int*)d_in[10];
    float*       out = (float*)d_out;
    float*       ws  = (float*)d_ws;

    main_kernel<<<NCOL + NPROJ, 256, 0, stream>>>(x, Wq, bq, Wk, bk, Wv, bv, bo,
                                                  seg, pos, ws, out);
    attn_kernel<<<HH * RSPLIT, 256, 0, stream>>>(Wv, bv, Wo, seg, pos, ws, out);
}